// Round 1
// baseline (162.206 us; speedup 1.0000x reference)
//
#include <hip/hip_runtime.h>

// Problem constants (fixed by the reference)
#define B_      16
#define N_      2048
#define M_      8192
#define ROWS    (B_ * N_)        // 32768
#define D_      8                // 4*2 flattened

// Kernel A tiling
#define SPLITS  16               // anchor splits
#define MSPLIT  (M_ / SPLITS)    // 512 anchors per split
#define BLK     256              // threads per block
#define RPT     8                // rows per thread
#define ROWS_PER_BLK (BLK * RPT) // 2048
#define ROWBLKS (ROWS / ROWS_PER_BLK) // 16

// Workspace layout: [ROWS][SPLITS] float scores, then [ROWS][SPLITS] int idx (4 MB total)
__global__ __launch_bounds__(BLK, 1) void argmin_part_kernel(
    const float* __restrict__ x,        // [ROWS][8]
    const float* __restrict__ anchors,  // [M_][8]
    float* __restrict__ ws_score,       // [ROWS][SPLITS]
    int*   __restrict__ ws_idx)         // [ROWS][SPLITS]
{
    __shared__ float sA[MSPLIT * D_];   // 16 KB: anchor tile
    __shared__ float sN[MSPLIT];        //  2 KB: ||a||^2

    const int split = blockIdx.y;
    const int tid   = threadIdx.x;

    // Stage this split's anchors into LDS (coalesced float4)
    const float4* gA = (const float4*)(anchors + (size_t)split * MSPLIT * D_);
    float4* lA = (float4*)sA;
    #pragma unroll
    for (int i = 0; i < (MSPLIT * 2) / BLK; ++i)   // 4 iters
        lA[tid + i * BLK] = gA[tid + i * BLK];
    __syncthreads();

    // Precompute anchor norms
    #pragma unroll
    for (int i = 0; i < MSPLIT / BLK; ++i) {       // 2 iters
        const int j = tid + i * BLK;
        const float* a = &sA[j * D_];
        float nr = a[0] * a[0];
        #pragma unroll
        for (int k = 1; k < D_; ++k) nr = fmaf(a[k], a[k], nr);
        sN[j] = nr;
    }
    __syncthreads();

    // Load my RPT rows into registers (coalesced: consecutive tids -> consecutive rows)
    const int row0 = blockIdx.x * ROWS_PER_BLK + tid;
    float xr[RPT][D_];
    #pragma unroll
    for (int r = 0; r < RPT; ++r) {
        const float4* px = (const float4*)(x + (size_t)(row0 + r * BLK) * D_);
        float4 lo = px[0], hi = px[1];
        xr[r][0] = lo.x; xr[r][1] = lo.y; xr[r][2] = lo.z; xr[r][3] = lo.w;
        xr[r][4] = hi.x; xr[r][5] = hi.y; xr[r][6] = hi.z; xr[r][7] = hi.w;
    }

    float best[RPT];
    int   bidx[RPT];
    #pragma unroll
    for (int r = 0; r < RPT; ++r) { best[r] = 3.4e38f; bidx[r] = 0; }

    const int base_idx = split * MSPLIT;

    // Scan anchors (ascending order + strict '<' == jnp.argmin first-index tie-break)
    #pragma unroll 2
    for (int j = 0; j < MSPLIT; ++j) {
        const float4 a0 = ((const float4*)sA)[j * 2];     // LDS broadcast (free)
        const float4 a1 = ((const float4*)sA)[j * 2 + 1];
        const float  nr = sN[j];
        const int    idx = base_idx + j;
        #pragma unroll
        for (int r = 0; r < RPT; ++r) {
            float d = xr[r][0] * a0.x;
            d = fmaf(xr[r][1], a0.y, d);
            d = fmaf(xr[r][2], a0.z, d);
            d = fmaf(xr[r][3], a0.w, d);
            d = fmaf(xr[r][4], a1.x, d);
            d = fmaf(xr[r][5], a1.y, d);
            d = fmaf(xr[r][6], a1.z, d);
            d = fmaf(xr[r][7], a1.w, d);
            const float s = fmaf(-2.0f, d, nr);
            const bool c = s < best[r];
            best[r] = c ? s   : best[r];
            bidx[r] = c ? idx : bidx[r];
        }
    }

    #pragma unroll
    for (int r = 0; r < RPT; ++r) {
        const int row = row0 + r * BLK;
        ws_score[(size_t)row * SPLITS + split] = best[r];
        ws_idx  [(size_t)row * SPLITS + split] = bidx[r];
    }
}

__global__ __launch_bounds__(256, 1) void combine_out_kernel(
    const float* __restrict__ x,        // [ROWS][8]
    const float* __restrict__ anchors,  // [M_][8]
    const float* __restrict__ sa_tab,   // [1000]
    const float* __restrict__ sb_tab,   // [1000]
    const int*   __restrict__ t,        // [B_]
    const float* __restrict__ ws_score,
    const int*   __restrict__ ws_idx,
    float* __restrict__ out)            // [ROWS][8]
{
    const int r = blockIdx.x * blockDim.x + threadIdx.x;
    if (r >= ROWS) return;

    float bs = 3.4e38f;
    int   bi = 0;
    // Ascending split order + strict '<' keeps the lowest anchor index on ties
    #pragma unroll
    for (int s = 0; s < SPLITS; ++s) {
        const float sc = ws_score[(size_t)r * SPLITS + s];
        const int   ix = ws_idx  [(size_t)r * SPLITS + s];
        const bool  c  = sc < bs;
        bs = c ? sc : bs;
        bi = c ? ix : bi;
    }

    const int b  = r >> 11;             // r / N_
    const int tb = t[b];
    const float sa = sa_tab[tb];
    const float sb = sb_tab[tb];

    const float4* px = (const float4*)(x + (size_t)r * D_);
    const float4* pa = (const float4*)(anchors + (size_t)bi * D_);
    const float4 x0 = px[0], x1 = px[1];
    const float4 a0 = pa[0], a1 = pa[1];

    float4 o0, o1;
    o0.x = sa * x0.x + sb * a0.x;
    o0.y = sa * x0.y + sb * a0.y;
    o0.z = sa * x0.z + sb * a0.z;
    o0.w = sa * x0.w + sb * a0.w;
    o1.x = sa * x1.x + sb * a1.x;
    o1.y = sa * x1.y + sb * a1.y;
    o1.z = sa * x1.z + sb * a1.z;
    o1.w = sa * x1.w + sb * a1.w;

    float4* po = (float4*)(out + (size_t)r * D_);
    po[0] = o0;
    po[1] = o1;
}

extern "C" void kernel_launch(void* const* d_in, const int* in_sizes, int n_in,
                              void* d_out, int out_size, void* d_ws, size_t ws_size,
                              hipStream_t stream) {
    const float* x       = (const float*)d_in[0];  // x_start [16,2048,4,2]
    const float* anchors = (const float*)d_in[1];  // anchors [8192,4,2]
    const float* sa_tab  = (const float*)d_in[2];  // sqrt_alphas_cumprod [1000]
    const float* sb_tab  = (const float*)d_in[3];  // sqrt_one_minus_alphas_cumprod [1000]
    const int*   t       = (const int*)d_in[4];    // t [16]
    float* out = (float*)d_out;

    float* ws_score = (float*)d_ws;
    int*   ws_idx   = (int*)((char*)d_ws + (size_t)ROWS * SPLITS * sizeof(float));

    dim3 gridA(ROWBLKS, SPLITS);   // 16 x 16 = 256 blocks
    argmin_part_kernel<<<gridA, BLK, 0, stream>>>(x, anchors, ws_score, ws_idx);

    combine_out_kernel<<<ROWS / 256, 256, 0, stream>>>(
        x, anchors, sa_tab, sb_tab, t, ws_score, ws_idx, out);
}

// Round 2
// 132.615 us; speedup vs baseline: 1.2231x; 1.2231x over previous
//
#include <hip/hip_runtime.h>
#include <stdint.h>

// Problem constants (fixed by the reference)
#define B_      16
#define N_      2048
#define M_      8192
#define ROWS    (B_ * N_)        // 32768
#define D_      8                // 4*2 flattened

// Kernel A tiling
#define SPLITS  64               // anchor splits  -> grid = 16 x 64 = 1024 blocks (4/CU)
#define MSPLIT  (M_ / SPLITS)    // 128 anchors per split
#define BLK     256              // threads per block
#define RPT     8                // rows per thread (amortizes LDS anchor reads 8x)
#define ROWS_PER_BLK (BLK * RPT) // 2048
#define ROWBLKS (ROWS / ROWS_PER_BLK) // 16

typedef float v2f __attribute__((ext_vector_type(2)));

// Monotone map float -> uint32 (preserves <). Equal floats -> equal keys, so
// u64 min over (key<<32 | idx) gives the smallest idx on ties == jnp.argmin.
__device__ __forceinline__ uint32_t f2key(float f) {
    uint32_t u = __float_as_uint(f);
    return u ^ (0x80000000u | (uint32_t)((int32_t)u >> 31));
}

// ws: [ROWS] u64, initialized to 0xFF..FF by hipMemsetAsync before launch.
__global__ __launch_bounds__(BLK) void argmin_part_kernel(
    const float* __restrict__ x,        // [ROWS][8]
    const float* __restrict__ anchors,  // [M_][8]
    unsigned long long* __restrict__ ws) // [ROWS] packed (key, idx)
{
    __shared__ float sA[MSPLIT * D_];   // 4 KB anchor tile
    __shared__ float sH[MSPLIT];        // 0.5*||a||^2

    const int split = blockIdx.y;
    const int tid   = threadIdx.x;

    // Stage this split's anchors into LDS: 128 anchors * 2 float4 = 256 float4
    const float4* gA = (const float4*)(anchors + (size_t)split * MSPLIT * D_);
    ((float4*)sA)[tid] = gA[tid];
    __syncthreads();

    // Half-norms (ordering-equivalent to nr - 2*dot: use 0.5*nr - dot)
    if (tid < MSPLIT) {
        const float* a = &sA[tid * D_];
        float nr = a[0] * a[0];
        #pragma unroll
        for (int k = 1; k < D_; ++k) nr = fmaf(a[k], a[k], nr);
        sH[tid] = 0.5f * nr;
    }
    __syncthreads();

    // Load my RPT rows into registers as float2 pairs (coalesced float4 loads)
    const int row0 = blockIdx.x * ROWS_PER_BLK + tid;
    v2f X[RPT][4];
    #pragma unroll
    for (int r = 0; r < RPT; ++r) {
        const float4* px = (const float4*)(x + (size_t)(row0 + r * BLK) * D_);
        float4 lo = px[0], hi = px[1];
        X[r][0] = (v2f){lo.x, lo.y};
        X[r][1] = (v2f){lo.z, lo.w};
        X[r][2] = (v2f){hi.x, hi.y};
        X[r][3] = (v2f){hi.z, hi.w};
    }

    float best[RPT];
    int   bidx[RPT];
    #pragma unroll
    for (int r = 0; r < RPT; ++r) { best[r] = 3.4e38f; bidx[r] = 0; }

    const int base_idx = split * MSPLIT;

    #pragma unroll 2
    for (int j = 0; j < MSPLIT; ++j) {
        const float4 a0 = ((const float4*)sA)[j * 2];     // LDS broadcast
        const float4 a1 = ((const float4*)sA)[j * 2 + 1];
        const float  hn = sH[j];
        const v2f A01 = (v2f){a0.x, a0.y};
        const v2f A23 = (v2f){a0.z, a0.w};
        const v2f A45 = (v2f){a1.x, a1.y};
        const v2f A67 = (v2f){a1.z, a1.w};
        const int idx = base_idx + j;
        #pragma unroll
        for (int r = 0; r < RPT; ++r) {
            v2f acc = X[r][0] * A01;                              // v_pk_mul_f32
            acc = __builtin_elementwise_fma(X[r][1], A23, acc);   // v_pk_fma_f32
            acc = __builtin_elementwise_fma(X[r][2], A45, acc);
            acc = __builtin_elementwise_fma(X[r][3], A67, acc);
            const float s = hn - acc[0] - acc[1];                 // smaller == closer
            const bool c = s < best[r];
            best[r] = c ? s   : best[r];
            bidx[r] = c ? idx : bidx[r];
        }
    }

    #pragma unroll
    for (int r = 0; r < RPT; ++r) {
        const int row = row0 + r * BLK;
        const unsigned long long packed =
            ((unsigned long long)f2key(best[r]) << 32) | (uint32_t)bidx[r];
        atomicMin(&ws[row], packed);
    }
}

__global__ __launch_bounds__(256) void combine_out_kernel(
    const float* __restrict__ x,        // [ROWS][8]
    const float* __restrict__ anchors,  // [M_][8]
    const float* __restrict__ sa_tab,   // [1000]
    const float* __restrict__ sb_tab,   // [1000]
    const int*   __restrict__ t,        // [B_]
    const unsigned long long* __restrict__ ws,
    float* __restrict__ out)            // [ROWS][8]
{
    const int r = blockIdx.x * blockDim.x + threadIdx.x;

    const int bi = (int)(ws[r] & 0xFFFFFFFFull);

    const int b  = r >> 11;             // r / N_
    const int tb = t[b];
    const float sa = sa_tab[tb];
    const float sb = sb_tab[tb];

    const float4* px = (const float4*)(x + (size_t)r * D_);
    const float4* pa = (const float4*)(anchors + (size_t)bi * D_);
    const float4 x0 = px[0], x1 = px[1];
    const float4 a0 = pa[0], a1 = pa[1];

    float4 o0, o1;
    o0.x = fmaf(sa, x0.x, sb * a0.x);
    o0.y = fmaf(sa, x0.y, sb * a0.y);
    o0.z = fmaf(sa, x0.z, sb * a0.z);
    o0.w = fmaf(sa, x0.w, sb * a0.w);
    o1.x = fmaf(sa, x1.x, sb * a1.x);
    o1.y = fmaf(sa, x1.y, sb * a1.y);
    o1.z = fmaf(sa, x1.z, sb * a1.z);
    o1.w = fmaf(sa, x1.w, sb * a1.w);

    float4* po = (float4*)(out + (size_t)r * D_);
    po[0] = o0;
    po[1] = o1;
}

extern "C" void kernel_launch(void* const* d_in, const int* in_sizes, int n_in,
                              void* d_out, int out_size, void* d_ws, size_t ws_size,
                              hipStream_t stream) {
    const float* x       = (const float*)d_in[0];  // x_start [16,2048,4,2]
    const float* anchors = (const float*)d_in[1];  // anchors [8192,4,2]
    const float* sa_tab  = (const float*)d_in[2];  // sqrt_alphas_cumprod [1000]
    const float* sb_tab  = (const float*)d_in[3];  // sqrt_one_minus_alphas_cumprod [1000]
    const int*   t       = (const int*)d_in[4];    // t [16]
    float* out = (float*)d_out;

    unsigned long long* ws = (unsigned long long*)d_ws;  // 256 KB

    // Init packed (key,idx) to +inf (all-ones). Graph-capture safe.
    hipMemsetAsync(ws, 0xFF, (size_t)ROWS * sizeof(unsigned long long), stream);

    dim3 gridA(ROWBLKS, SPLITS);   // 16 x 64 = 1024 blocks -> 4 blocks/CU
    argmin_part_kernel<<<gridA, BLK, 0, stream>>>(x, anchors, ws);

    combine_out_kernel<<<ROWS / 256, 256, 0, stream>>>(
        x, anchors, sa_tab, sb_tab, t, ws, out);
}